// Round 1
// baseline (234.430 us; speedup 1.0000x reference)
//
#include <hip/hip_runtime.h>
#include <hip/hip_bf16.h>

#define IN_F 8192
#define OUT_F 8192
#define SEQ 64
#define LORA_R 16
#define KH 4096            // K per split-K half

typedef __attribute__((ext_vector_type(4))) float f32x4;
typedef __attribute__((ext_vector_type(4))) int i32x4;
typedef __attribute__((ext_vector_type(8))) unsigned short u16x8;
typedef __attribute__((ext_vector_type(4))) unsigned short u16x4;
typedef _Float16 f16x2 __attribute__((ext_vector_type(2)));
typedef _Float16 f16x8 __attribute__((ext_vector_type(8)));

// ---- prep (fused): xb = fp16(x); t = x @ A^T. One block per s-row. ----
__global__ __launch_bounds__(256) void k_prep(
    const float* __restrict__ x, const float* __restrict__ A,
    unsigned short* __restrict__ xb, float* __restrict__ t) {
    __shared__ float part[64];
    const int s = blockIdx.x;
    const int w = threadIdx.x >> 6, lane = threadIdx.x & 63;
    const int kbase = w * 2048;             // 4 waves x 2048-wide K chunks
    const float* xr = x + s * IN_F + kbase;

    f32x4 xv[8];
    #pragma unroll
    for (int j = 0; j < 8; ++j) {
        xv[j] = *(const f32x4*)(xr + j * 256 + lane * 4);
        u16x4 h;
        h[0] = __builtin_bit_cast(unsigned short, (_Float16)xv[j].x);
        h[1] = __builtin_bit_cast(unsigned short, (_Float16)xv[j].y);
        h[2] = __builtin_bit_cast(unsigned short, (_Float16)xv[j].z);
        h[3] = __builtin_bit_cast(unsigned short, (_Float16)xv[j].w);
        *(u16x4*)(xb + s * IN_F + kbase + j * 256 + lane * 4) = h;
    }

    float acc[LORA_R];
    #pragma unroll
    for (int r = 0; r < LORA_R; ++r) acc[r] = 0.f;
    #pragma unroll
    for (int r = 0; r < LORA_R; ++r) {
        const float* ar = A + r * IN_F + kbase;
        #pragma unroll
        for (int j = 0; j < 8; ++j) {
            f32x4 av = *(const f32x4*)(ar + j * 256 + lane * 4);
            acc[r] = fmaf(xv[j].x, av.x, acc[r]);
            acc[r] = fmaf(xv[j].y, av.y, acc[r]);
            acc[r] = fmaf(xv[j].z, av.z, acc[r]);
            acc[r] = fmaf(xv[j].w, av.w, acc[r]);
        }
    }
    #pragma unroll
    for (int r = 0; r < LORA_R; ++r) {
        float v = acc[r];
        #pragma unroll
        for (int off = 32; off; off >>= 1) v += __shfl_down(v, off, 64);
        if (lane == 0) part[w * 16 + r] = v;
    }
    __syncthreads();
    if (threadIdx.x < 16)
        t[s * LORA_R + threadIdx.x] = part[threadIdx.x] + part[16 + threadIdx.x] +
                                      part[32 + threadIdx.x] + part[48 + threadIdx.x];
}

// ---- main: 512 blocks = 256 n-tiles(32 cols) x 2 K-halves; 512 thr = 8 waves ----
// waves: (nh = w>>2) n-half, (wkk = w&3) k32 sub-step of the BK=128 chunk.
// LDS (60928 B): xs [2][64*136] f16 | wt [2][32*68] int | scs [32*68] f32
// epilogue alias: accs [8][64*17] f32 over xs.
__global__ __launch_bounds__(512, 4) void k_main(
    const int* __restrict__ packed, const float* __restrict__ scales,
    const unsigned short* __restrict__ xb, const float* __restrict__ t,
    const float* __restrict__ B, float* __restrict__ out) {
    __shared__ char lds[60928];
    _Float16* xs = (_Float16*)lds;
    int* wt = (int*)(lds + 34816);
    float* scs = (float*)(lds + 52224);
    float* accs = (float*)lds;

    const int tid = threadIdx.x;
    const int n0 = (blockIdx.x >> 1) * 32;
    const int kh = blockIdx.x & 1;
    const int w = tid >> 6, lane = tid & 63;
    const int nh = w >> 2, wkk = w & 3;
    const int q = lane >> 4, c16 = lane & 15;

    // scales for this block's 32 rows, this K-half (64 blocks each), staged once
    {
        int row = tid >> 4, g = tid & 15;
        f32x4 v = *(const f32x4*)(scales + (n0 + row) * (IN_F / 64) + kh * 64 + g * 4);
        *(f32x4*)(scs + row * 68 + g * 4) = v;
    }

    // staging coords
    const int xrow = tid >> 3, xseg = tid & 7;   // 64 rows x 8 segs x 16 halves
    const int wrow = tid >> 4, wg = tid & 15;    // 32 rows x 16 segs x 4 ints
    const unsigned short* xsrc = xb + xrow * IN_F + kh * KH + xseg * 16;
    const int* wsrc = packed + (long)(n0 + wrow) * (IN_F / 2) + kh * (KH / 2) + wg * 4;

    f32x4 acc[4];
    #pragma unroll
    for (int mt = 0; mt < 4; ++mt) acc[mt] = (f32x4){0.f, 0.f, 0.f, 0.f};

    u16x8 gx0, gx1; i32x4 gw;
    gx0 = *(const u16x8*)(xsrc);
    gx1 = *(const u16x8*)(xsrc + 8);
    gw  = *(const i32x4*)(wsrc);
    *(u16x8*)(xs + xrow * 136 + xseg * 16)     = gx0;
    *(u16x8*)(xs + xrow * 136 + xseg * 16 + 8) = gx1;
    *(i32x4*)(wt + wrow * 68 + wg * 4)         = gw;
    __syncthreads();

    const f16x2 c1032 = {(_Float16)1032.0f, (_Float16)1032.0f};

    for (int kt = 0; kt < 32; ++kt) {
        const int cur = kt & 1;
        if (kt < 31) {   // prefetch next BK chunk (coalesced 256B segments)
            gx0 = *(const u16x8*)(xsrc + (kt + 1) * 128);
            gx1 = *(const u16x8*)(xsrc + (kt + 1) * 128 + 8);
            gw  = *(const i32x4*)(wsrc + (kt + 1) * 64);
        }
        // compute current buffer
        i32x4 pv = *(const i32x4*)(wt + cur * (32 * 68) + (nh * 16 + c16) * 68 + wkk * 16 + q * 4);
        float scf = scs[(nh * 16 + c16) * 68 + kt * 2 + (wkk >> 1)];
        _Float16 sch = (_Float16)scf;
        f16x2 sc2 = {sch, sch};
        f16x8 bf;
        #pragma unroll
        for (int m = 0; m < 4; ++m) {
            unsigned u = ((((unsigned)pv[m] << 12) | (unsigned)pv[m]) & 0x000F000Fu) | 0x64006400u;
            f16x2 h = __builtin_bit_cast(f16x2, u);
            h = (h - c1032) * sc2;          // exact (q-8)*scale
            bf[2 * m] = h.x;
            bf[2 * m + 1] = h.y;
        }
        const _Float16* xbase = xs + cur * (64 * 136) + wkk * 32 + q * 8;
        #pragma unroll
        for (int mt = 0; mt < 4; ++mt) {
            f16x8 af = *(const f16x8*)(xbase + (mt * 16 + c16) * 136);
            acc[mt] = __builtin_amdgcn_mfma_f32_16x16x32_f16(af, bf, acc[mt], 0, 0, 0);
        }
        __syncthreads();
        if (kt < 31) {
            *(u16x8*)(xs + (1 - cur) * (64 * 136) + xrow * 136 + xseg * 16)     = gx0;
            *(u16x8*)(xs + (1 - cur) * (64 * 136) + xrow * 136 + xseg * 16 + 8) = gx1;
            *(i32x4*)(wt + (1 - cur) * (32 * 68) + wrow * 68 + wg * 4)          = gw;
        }
        __syncthreads();
    }

    // epilogue: per-wave partials -> LDS (alias), reduce 4 k-waves, LoRA (kh0), atomic out
    float* myacc = accs + w * (64 * 17);
    #pragma unroll
    for (int mt = 0; mt < 4; ++mt)
        #pragma unroll
        for (int r = 0; r < 4; ++r)
            myacc[(mt * 16 + q * 4 + r) * 17 + c16] = acc[mt][r];
    __syncthreads();

    #pragma unroll
    for (int j = 0; j < 4; ++j) {
        int p = tid + j * 512;                    // 2048 outputs: s in 0..63, c in 0..31
        int s = p >> 5, c = p & 31;
        const float* ab = accs + (c >> 4) * 4 * (64 * 17) + s * 17 + (c & 15);
        float v = ab[0] + ab[64 * 17] + ab[2 * 64 * 17] + ab[3 * 64 * 17];
        if (kh == 0) {
            const float* tp = t + s * LORA_R;
            const float* bp = B + (n0 + c) * LORA_R;
            f32x4 t0 = *(const f32x4*)tp,       t1 = *(const f32x4*)(tp + 4);
            f32x4 t2 = *(const f32x4*)(tp + 8), t3 = *(const f32x4*)(tp + 12);
            f32x4 b0 = *(const f32x4*)bp,       b1 = *(const f32x4*)(bp + 4);
            f32x4 b2 = *(const f32x4*)(bp + 8), b3 = *(const f32x4*)(bp + 12);
            float lr = t0.x * b0.x + t0.y * b0.y + t0.z * b0.z + t0.w * b0.w
                     + t1.x * b1.x + t1.y * b1.y + t1.z * b1.z + t1.w * b1.w
                     + t2.x * b2.x + t2.y * b2.y + t2.z * b2.z + t2.w * b2.w
                     + t3.x * b3.x + t3.y * b3.y + t3.z * b3.z + t3.w * b3.w;
            v += 2.0f * lr;
        }
        unsafeAtomicAdd(&out[s * OUT_F + n0 + c], v);
    }
}

extern "C" void kernel_launch(void* const* d_in, const int* in_sizes, int n_in,
                              void* d_out, int out_size, void* d_ws, size_t ws_size,
                              hipStream_t stream) {
    const float* x      = (const float*)d_in[0];
    const int* packed   = (const int*)d_in[1];
    const float* scales = (const float*)d_in[2];
    const float* lora_A = (const float*)d_in[3];
    const float* lora_B = (const float*)d_in[4];
    float* out = (float*)d_out;

    unsigned short* xb = (unsigned short*)d_ws;                 // 1 MiB fp16 x
    float* t = (float*)((char*)d_ws + (size_t)SEQ * IN_F * 2);  // 4 KiB

    hipMemsetAsync(out, 0, (size_t)SEQ * OUT_F * sizeof(float), stream);
    k_prep<<<SEQ, 256, 0, stream>>>(x, lora_A, xb, t);
    k_main<<<512, 512, 0, stream>>>(packed, scales, xb, t, lora_B, out);
}

// Round 2
// 233.141 us; speedup vs baseline: 1.0055x; 1.0055x over previous
//
#include <hip/hip_runtime.h>
#include <hip/hip_bf16.h>

#define IN_F 8192
#define OUT_F 8192
#define SEQ 64
#define LORA_R 16
#define KH 4096            // K per split-K half

typedef __attribute__((ext_vector_type(4))) float f32x4;
typedef __attribute__((ext_vector_type(4))) int i32x4;
typedef __attribute__((ext_vector_type(8))) unsigned short u16x8;
typedef __attribute__((ext_vector_type(4))) unsigned short u16x4;
typedef _Float16 f16x2 __attribute__((ext_vector_type(2)));
typedef _Float16 f16x8 __attribute__((ext_vector_type(8)));

typedef __attribute__((address_space(3))) unsigned int lds_u32;
typedef const __attribute__((address_space(1))) unsigned int glb_u32;

// async global->LDS, 16B per lane; LDS dest = wave-uniform base + lane*16
__device__ __forceinline__ void gl_lds16(const void* g, void* l) {
    __builtin_amdgcn_global_load_lds((glb_u32*)g, (lds_u32*)l, 16, 0, 0);
}

// ---- prep (fused): xb = fp16(x); t = x @ A^T. One block per s-row. ----
__global__ __launch_bounds__(256) void k_prep(
    const float* __restrict__ x, const float* __restrict__ A,
    unsigned short* __restrict__ xb, float* __restrict__ t) {
    __shared__ float part[64];
    const int s = blockIdx.x;
    const int w = threadIdx.x >> 6, lane = threadIdx.x & 63;
    const int kbase = w * 2048;
    const float* xr = x + s * IN_F + kbase;

    f32x4 xv[8];
    #pragma unroll
    for (int j = 0; j < 8; ++j) {
        xv[j] = *(const f32x4*)(xr + j * 256 + lane * 4);
        u16x4 h;
        h[0] = __builtin_bit_cast(unsigned short, (_Float16)xv[j].x);
        h[1] = __builtin_bit_cast(unsigned short, (_Float16)xv[j].y);
        h[2] = __builtin_bit_cast(unsigned short, (_Float16)xv[j].z);
        h[3] = __builtin_bit_cast(unsigned short, (_Float16)xv[j].w);
        *(u16x4*)(xb + s * IN_F + kbase + j * 256 + lane * 4) = h;
    }

    float acc[LORA_R];
    #pragma unroll
    for (int r = 0; r < LORA_R; ++r) acc[r] = 0.f;
    #pragma unroll
    for (int r = 0; r < LORA_R; ++r) {
        const float* ar = A + r * IN_F + kbase;
        #pragma unroll
        for (int j = 0; j < 8; ++j) {
            f32x4 av = *(const f32x4*)(ar + j * 256 + lane * 4);
            acc[r] = fmaf(xv[j].x, av.x, acc[r]);
            acc[r] = fmaf(xv[j].y, av.y, acc[r]);
            acc[r] = fmaf(xv[j].z, av.z, acc[r]);
            acc[r] = fmaf(xv[j].w, av.w, acc[r]);
        }
    }
    #pragma unroll
    for (int r = 0; r < LORA_R; ++r) {
        float v = acc[r];
        #pragma unroll
        for (int off = 32; off; off >>= 1) v += __shfl_down(v, off, 64);
        if (lane == 0) part[w * 16 + r] = v;
    }
    __syncthreads();
    if (threadIdx.x < 16)
        t[s * LORA_R + threadIdx.x] = part[threadIdx.x] + part[16 + threadIdx.x] +
                                      part[32 + threadIdx.x] + part[48 + threadIdx.x];
}

// ---- main: 512 blocks = 256 n-tiles(32 cols) x 2 K-halves; 512 thr = 8 waves ----
// Staging via global_load_lds (linear LDS dest); XOR swizzle (16B slot ^= row&7)
// baked into the per-lane GLOBAL source address and applied on the LDS reads.
// One raw s_barrier per kt; vmcnt drains the chunk issued a FULL iteration ago.
// LDS (57856 B): xs [2][64*128] f16 | wt [2][32*64] int | scs [32*68] f32
// epilogue alias: accs [8][64*17] f32 over xs/wt.
__global__ __launch_bounds__(512, 4) void k_main(
    const int* __restrict__ packed, const float* __restrict__ scales,
    const unsigned short* __restrict__ xb, const float* __restrict__ t,
    const float* __restrict__ B, float* __restrict__ out) {
    __shared__ char lds[57856];
    _Float16* xs = (_Float16*)lds;            // 2 x 8192 halves (32768 B)
    int* wt = (int*)(lds + 32768);            // 2 x 2048 ints  (16384 B)
    float* scs = (float*)(lds + 49152);       // 32*68 f32      (8704 B)
    float* accs = (float*)lds;

    const int tid = threadIdx.x;
    const int n0 = (blockIdx.x >> 1) * 32;
    const int kh = blockIdx.x & 1;
    const int w = tid >> 6, lane = tid & 63;
    const int nh = w >> 2, wkk = w & 3;
    const int q = lane >> 4, c16 = lane & 15;

    // per-lane staging sources, column slot pre-XOR'd with (row&7)
    const int lrow = lane >> 4, lcol = lane & 15;
    const int xr0 = w * 8 + lrow, xr1 = xr0 + 4;
    const int wr  = w * 4 + lrow;
    const unsigned short* xg0 = xb + (size_t)xr0 * IN_F + kh * KH + ((lcol ^ (xr0 & 7)) << 3);
    const unsigned short* xg1 = xb + (size_t)xr1 * IN_F + kh * KH + ((lcol ^ (xr1 & 7)) << 3);
    const int* wgp = packed + (long)(n0 + wr) * (IN_F / 2) + kh * (KH / 2) + ((lcol ^ (wr & 7)) << 2);

    // wave-uniform LDS dests (buffer 0)
    _Float16* xd0 = xs + w * 8 * 128;
    _Float16* xd1 = xd0 + 4 * 128;
    int* wd = wt + w * 256;

    // scales for this block's 32 rows, this K-half, staged once
    {
        int row = tid >> 4, g = tid & 15;
        f32x4 v = *(const f32x4*)(scales + (n0 + row) * (IN_F / 64) + kh * 64 + g * 4);
        *(f32x4*)(scs + row * 68 + g * 4) = v;
    }

    f32x4 acc[4];
    #pragma unroll
    for (int mt = 0; mt < 4; ++mt) acc[mt] = (f32x4){0.f, 0.f, 0.f, 0.f};

    // loop-invariant swizzled read offsets
    const int pvo = (nh * 16 + c16) * 64 + ((wkk * 16 + q * 4) ^ ((c16 & 7) << 2));
    int afo[4];
    #pragma unroll
    for (int mt = 0; mt < 4; ++mt)
        afo[mt] = (mt * 16 + c16) * 128 + ((wkk * 32 + q * 8) ^ ((c16 & 7) << 3));
    const int sco = (nh * 16 + c16) * 68 + (wkk >> 1);

    // prologue: stage chunk 0 -> buffer 0
    gl_lds16(xg0, xd0);
    gl_lds16(xg1, xd1);
    gl_lds16(wgp, wd);

    const f16x2 c1032 = {(_Float16)1032.0f, (_Float16)1032.0f};

    for (int kt = 0; kt < 32; ++kt) {
        // own staged chunk (issued last iter) resident + own LDS ops drained, then sync
        asm volatile("s_waitcnt vmcnt(0) lgkmcnt(0)" ::: "memory");
        __builtin_amdgcn_s_barrier();
        __builtin_amdgcn_sched_barrier(0);
        const int cur = kt & 1;
        if (kt < 31) {   // issue next chunk -> other buffer; waited at next iter's top
            const int nb = 1 - cur;
            const size_t xoff = (size_t)(kt + 1) * 128;
            gl_lds16(xg0 + xoff, xd0 + nb * 8192);
            gl_lds16(xg1 + xoff, xd1 + nb * 8192);
            gl_lds16(wgp + (kt + 1) * 64, wd + nb * 2048);
        }
        i32x4 pv = *(const i32x4*)(wt + cur * 2048 + pvo);
        float scf = scs[sco + kt * 2];
        _Float16 sch = (_Float16)scf;
        f16x2 sc2 = {sch, sch};
        f16x8 bf;
        #pragma unroll
        for (int m = 0; m < 4; ++m) {
            unsigned u = ((((unsigned)pv[m] << 12) | (unsigned)pv[m]) & 0x000F000Fu) | 0x64006400u;
            f16x2 h = __builtin_bit_cast(f16x2, u);
            h = (h - c1032) * sc2;          // exact (q-8)*scale
            bf[2 * m] = h.x;
            bf[2 * m + 1] = h.y;
        }
        const _Float16* xbase = xs + cur * 8192;
        #pragma unroll
        for (int mt = 0; mt < 4; ++mt) {
            f16x8 af = *(const f16x8*)(xbase + afo[mt]);
            acc[mt] = __builtin_amdgcn_mfma_f32_16x16x32_f16(af, bf, acc[mt], 0, 0, 0);
        }
    }
    __syncthreads();   // all waves done with xs/wt before alias overwrite

    // epilogue: per-wave partials -> LDS (alias), reduce 4 k-waves, LoRA (kh0), atomic out
    float* myacc = accs + w * (64 * 17);
    #pragma unroll
    for (int mt = 0; mt < 4; ++mt)
        #pragma unroll
        for (int r = 0; r < 4; ++r)
            myacc[(mt * 16 + q * 4 + r) * 17 + c16] = acc[mt][r];
    __syncthreads();

    #pragma unroll
    for (int j = 0; j < 4; ++j) {
        int p = tid + j * 512;                    // 2048 outputs: s in 0..63, c in 0..31
        int s = p >> 5, c = p & 31;
        const float* ab = accs + (c >> 4) * 4 * (64 * 17) + s * 17 + (c & 15);
        float v = ab[0] + ab[64 * 17] + ab[2 * 64 * 17] + ab[3 * 64 * 17];
        if (kh == 0) {
            const float* tp = t + s * LORA_R;
            const float* bp = B + (n0 + c) * LORA_R;
            f32x4 t0 = *(const f32x4*)tp,       t1 = *(const f32x4*)(tp + 4);
            f32x4 t2 = *(const f32x4*)(tp + 8), t3 = *(const f32x4*)(tp + 12);
            f32x4 b0 = *(const f32x4*)bp,       b1 = *(const f32x4*)(bp + 4);
            f32x4 b2 = *(const f32x4*)(bp + 8), b3 = *(const f32x4*)(bp + 12);
            float lr = t0.x * b0.x + t0.y * b0.y + t0.z * b0.z + t0.w * b0.w
                     + t1.x * b1.x + t1.y * b1.y + t1.z * b1.z + t1.w * b1.w
                     + t2.x * b2.x + t2.y * b2.y + t2.z * b2.z + t2.w * b2.w
                     + t3.x * b3.x + t3.y * b3.y + t3.z * b3.z + t3.w * b3.w;
            v += 2.0f * lr;
        }
        unsafeAtomicAdd(&out[s * OUT_F + n0 + c], v);
    }
}

extern "C" void kernel_launch(void* const* d_in, const int* in_sizes, int n_in,
                              void* d_out, int out_size, void* d_ws, size_t ws_size,
                              hipStream_t stream) {
    const float* x      = (const float*)d_in[0];
    const int* packed   = (const int*)d_in[1];
    const float* scales = (const float*)d_in[2];
    const float* lora_A = (const float*)d_in[3];
    const float* lora_B = (const float*)d_in[4];
    float* out = (float*)d_out;

    unsigned short* xb = (unsigned short*)d_ws;                 // 1 MiB fp16 x
    float* t = (float*)((char*)d_ws + (size_t)SEQ * IN_F * 2);  // 4 KiB

    hipMemsetAsync(out, 0, (size_t)SEQ * OUT_F * sizeof(float), stream);
    k_prep<<<SEQ, 256, 0, stream>>>(x, lora_A, xb, t);
    k_main<<<512, 512, 0, stream>>>(packed, scales, xb, t, lora_B, out);
}

// Round 4
// 221.006 us; speedup vs baseline: 1.0607x; 1.0549x over previous
//
#include <hip/hip_runtime.h>
#include <hip/hip_bf16.h>

#define IN_F 8192
#define OUT_F 8192
#define SEQ 64
#define LORA_R 16

typedef __attribute__((ext_vector_type(4))) float f32x4;
typedef __attribute__((ext_vector_type(4))) int i32x4;
typedef __attribute__((ext_vector_type(8))) unsigned short u16x8;
typedef __attribute__((ext_vector_type(4))) unsigned short u16x4;
typedef _Float16 f16x2 __attribute__((ext_vector_type(2)));
typedef _Float16 f16x8 __attribute__((ext_vector_type(8)));

typedef __attribute__((address_space(3))) unsigned int lds_u32;
typedef const __attribute__((address_space(1))) unsigned int glb_u32;

__device__ __forceinline__ void gl_lds16(const void* g, void* l) {
    __builtin_amdgcn_global_load_lds((glb_u32*)g, (lds_u32*)l, 16, 0, 0);
}

// ---- prep: xb = fp16(x); t partials = x @ A^T (K split in 2). 128 blocks. ----
__global__ __launch_bounds__(256) void k_prep(
    const float* __restrict__ x, const float* __restrict__ A,
    unsigned short* __restrict__ xb, float* __restrict__ t) {
    __shared__ float part[64];
    const int s = blockIdx.x >> 1, p = blockIdx.x & 1;
    const int w = threadIdx.x >> 6, lane = threadIdx.x & 63;
    const int kbase = p * 4096 + w * 1024;
    const float* xr = x + s * IN_F + kbase;

    f32x4 xv[4];
    #pragma unroll
    for (int j = 0; j < 4; ++j) {
        xv[j] = *(const f32x4*)(xr + j * 256 + lane * 4);
        u16x4 h;
        h[0] = __builtin_bit_cast(unsigned short, (_Float16)xv[j].x);
        h[1] = __builtin_bit_cast(unsigned short, (_Float16)xv[j].y);
        h[2] = __builtin_bit_cast(unsigned short, (_Float16)xv[j].z);
        h[3] = __builtin_bit_cast(unsigned short, (_Float16)xv[j].w);
        *(u16x4*)(xb + s * IN_F + kbase + j * 256 + lane * 4) = h;
    }

    float acc[LORA_R];
    #pragma unroll
    for (int r = 0; r < LORA_R; ++r) acc[r] = 0.f;
    #pragma unroll
    for (int r = 0; r < LORA_R; ++r) {
        const float* ar = A + r * IN_F + kbase;
        #pragma unroll
        for (int j = 0; j < 4; ++j) {
            f32x4 av = *(const f32x4*)(ar + j * 256 + lane * 4);
            acc[r] = fmaf(xv[j].x, av.x, acc[r]);
            acc[r] = fmaf(xv[j].y, av.y, acc[r]);
            acc[r] = fmaf(xv[j].z, av.z, acc[r]);
            acc[r] = fmaf(xv[j].w, av.w, acc[r]);
        }
    }
    #pragma unroll
    for (int r = 0; r < LORA_R; ++r) {
        float v = acc[r];
        #pragma unroll
        for (int off = 32; off; off >>= 1) v += __shfl_down(v, off, 64);
        if (lane == 0) part[w * 16 + r] = v;
    }
    __syncthreads();
    if (threadIdx.x < 16)
        t[s * 32 + p * 16 + threadIdx.x] = part[threadIdx.x] + part[16 + threadIdx.x] +
                                           part[32 + threadIdx.x] + part[48 + threadIdx.x];
}

// ---- main: 256 blocks (one 32-col n-tile each, FULL K), 512 thr = 8 waves ----
// No split-K: direct stores, no atomics, no out-memset.
// Staging: global_load_lds w/ pre-XOR'd global src + swizzled LDS reads (rule #21).
// 2-deep pipeline over 3 LDS buffers, counted s_waitcnt vmcnt(3) (T4).
// LDS (90624 B): xs 3x[64*128]f16 | wt 3x[32*64]int | scs [32*132]f32
// epilogue alias: accs [8][64*17] f32 over xs.
__global__ __launch_bounds__(512, 2) void k_main(
    const int* __restrict__ packed, const float* __restrict__ scales,
    const unsigned short* __restrict__ xb, const float* __restrict__ t,
    const float* __restrict__ B, float* __restrict__ out) {
    __shared__ char lds[90624];
    _Float16* xs = (_Float16*)lds;            // 3 x 16384 B
    int* wt = (int*)(lds + 49152);            // 3 x 8192 B
    float* scs = (float*)(lds + 73728);       // 32*132*4 = 16896 B
    float* accs = (float*)lds;

    const int tid = threadIdx.x;
    const int n0 = blockIdx.x * 32;
    const int w = tid >> 6, lane = tid & 63;
    const int nh = w >> 2, wkk = w & 3;
    const int q = lane >> 4, c16 = lane & 15;

    // per-lane staging sources, 16B slot pre-XOR'd with (row&7)
    const int lrow = lane >> 4, lcol = lane & 15;
    const int xr0 = w * 8 + lrow, xr1 = xr0 + 4;
    const int wr  = w * 4 + lrow;
    const unsigned short* xg0 = xb + (size_t)xr0 * IN_F + ((lcol ^ (xr0 & 7)) << 3);
    const unsigned short* xg1 = xb + (size_t)xr1 * IN_F + ((lcol ^ (xr1 & 7)) << 3);
    const int* wgp = packed + (long)(n0 + wr) * (IN_F / 2) + ((lcol ^ (wr & 7)) << 2);

    // wave-uniform LDS dest bases (buffer 0)
    _Float16* xd0 = xs + w * 8 * 128;
    _Float16* xd1 = xd0 + 4 * 128;
    int* wd = wt + w * 256;

    // stage all 128 scales for this tile's 32 rows
    {
        int row = tid >> 4, g = tid & 15;
        const float* sp = scales + (n0 + row) * (IN_F / 64);
        *(f32x4*)(scs + row * 132 + g * 4)      = *(const f32x4*)(sp + g * 4);
        *(f32x4*)(scs + row * 132 + 64 + g * 4) = *(const f32x4*)(sp + 64 + g * 4);
    }

    f32x4 acc[4];
    #pragma unroll
    for (int mt = 0; mt < 4; ++mt) acc[mt] = (f32x4){0.f, 0.f, 0.f, 0.f};

    // loop-invariant swizzled read offsets
    const int pvo = (nh * 16 + c16) * 64 + ((wkk * 16 + q * 4) ^ ((c16 & 7) << 2));
    int afo[4];
    #pragma unroll
    for (int mt = 0; mt < 4; ++mt)
        afo[mt] = (mt * 16 + c16) * 128 + ((wkk * 32 + q * 8) ^ ((c16 & 7) << 3));
    const int sco = (nh * 16 + c16) * 132 + (wkk >> 1);

    // make scs visible before anyone reads it (LDS drain only — keep vm queue free)
    asm volatile("s_waitcnt lgkmcnt(0)" ::: "memory");
    __builtin_amdgcn_s_barrier();

    // prologue: stage chunks 0,1 -> buffers 0,1 (2-deep)
    gl_lds16(xg0, xd0);
    gl_lds16(xg1, xd1);
    gl_lds16(wgp, wd);
    gl_lds16(xg0 + 128, xd0 + 8192);
    gl_lds16(xg1 + 128, xd1 + 8192);
    gl_lds16(wgp + 64,  wd + 2048);

    const f16x2 c1032 = {(_Float16)1032.0f, (_Float16)1032.0f};

    int cur = 0, nxt = 2;   // chunk kt lives in buf kt%3; issue target = (kt+2)%3
    for (int kt = 0; kt < 64; ++kt) {
        // chunk kt resident (3 newest loads may still fly); barrier; then issue kt+2
        if (kt < 63) asm volatile("s_waitcnt vmcnt(3)" ::: "memory");
        else         asm volatile("s_waitcnt vmcnt(0)" ::: "memory");
        __builtin_amdgcn_s_barrier();
        __builtin_amdgcn_sched_barrier(0);
        if (kt < 62) {
            const size_t xoff = (size_t)(kt + 2) * 128;
            gl_lds16(xg0 + xoff, xd0 + nxt * 8192);
            gl_lds16(xg1 + xoff, xd1 + nxt * 8192);
            gl_lds16(wgp + (kt + 2) * 64, wd + nxt * 2048);
        }
        i32x4 pv = *(const i32x4*)(wt + cur * 2048 + pvo);
        float scf = scs[sco + kt * 2];
        _Float16 sch = (_Float16)scf;
        f16x2 sc2 = {sch, sch};
        f16x8 bf;
        #pragma unroll
        for (int m = 0; m < 4; ++m) {
            unsigned u = ((((unsigned)pv[m] << 12) | (unsigned)pv[m]) & 0x000F000Fu) | 0x64006400u;
            f16x2 h = __builtin_bit_cast(f16x2, u);
            h = (h - c1032) * sc2;          // exact (q-8)*scale
            bf[2 * m] = h.x;
            bf[2 * m + 1] = h.y;
        }
        const _Float16* xbase = xs + cur * 8192;
        #pragma unroll
        for (int mt = 0; mt < 4; ++mt) {
            f16x8 af = *(const f16x8*)(xbase + afo[mt]);
            acc[mt] = __builtin_amdgcn_mfma_f32_16x16x32_f16(af, bf, acc[mt], 0, 0, 0);
        }
        cur = (cur == 2) ? 0 : cur + 1;
        nxt = (nxt == 2) ? 0 : nxt + 1;
    }
    __syncthreads();   // all waves done with xs/wt before alias overwrite

    // epilogue: per-wave partials -> LDS (alias), reduce 4 k-waves, LoRA, store
    float* myacc = accs + w * (64 * 17);
    #pragma unroll
    for (int mt = 0; mt < 4; ++mt)
        #pragma unroll
        for (int r = 0; r < 4; ++r)
            myacc[(mt * 16 + q * 4 + r) * 17 + c16] = acc[mt][r];
    __syncthreads();

    #pragma unroll
    for (int j = 0; j < 4; ++j) {
        int p = tid + j * 512;                    // 2048 outputs: s in 0..63, c in 0..31
        int s = p >> 5, c = p & 31;
        const float* ab = accs + (c >> 4) * 4 * (64 * 17) + s * 17 + (c & 15);
        float v = ab[0] + ab[64 * 17] + ab[2 * 64 * 17] + ab[3 * 64 * 17];
        const float* tp = t + s * 32;             // two K-half partials of x@A^T
        const float* bp = B + (n0 + c) * LORA_R;
        f32x4 t0 = *(const f32x4*)tp        + *(const f32x4*)(tp + 16);
        f32x4 t1 = *(const f32x4*)(tp + 4)  + *(const f32x4*)(tp + 20);
        f32x4 t2 = *(const f32x4*)(tp + 8)  + *(const f32x4*)(tp + 24);
        f32x4 t3 = *(const f32x4*)(tp + 12) + *(const f32x4*)(tp + 28);
        f32x4 b0 = *(const f32x4*)bp,       b1 = *(const f32x4*)(bp + 4);
        f32x4 b2 = *(const f32x4*)(bp + 8), b3 = *(const f32x4*)(bp + 12);
        float lr = t0.x * b0.x + t0.y * b0.y + t0.z * b0.z + t0.w * b0.w
                 + t1.x * b1.x + t1.y * b1.y + t1.z * b1.z + t1.w * b1.w
                 + t2.x * b2.x + t2.y * b2.y + t2.z * b2.z + t2.w * b2.w
                 + t3.x * b3.x + t3.y * b3.y + t3.z * b3.z + t3.w * b3.w;
        v += 2.0f * lr;
        out[s * OUT_F + n0 + c] = v;
    }
}

extern "C" void kernel_launch(void* const* d_in, const int* in_sizes, int n_in,
                              void* d_out, int out_size, void* d_ws, size_t ws_size,
                              hipStream_t stream) {
    const float* x      = (const float*)d_in[0];
    const int* packed   = (const int*)d_in[1];
    const float* scales = (const float*)d_in[2];
    const float* lora_A = (const float*)d_in[3];
    const float* lora_B = (const float*)d_in[4];
    float* out = (float*)d_out;

    unsigned short* xb = (unsigned short*)d_ws;                    // 1 MiB fp16 x
    float* t = (float*)((char*)d_ws + (size_t)SEQ * IN_F * 2);     // 8 KiB partials

    k_prep<<<128, 256, 0, stream>>>(x, lora_A, xb, t);
    k_main<<<256, 512, 0, stream>>>(packed, scales, xb, t, lora_B, out);
}

// Round 5
// 217.092 us; speedup vs baseline: 1.0799x; 1.0180x over previous
//
#include <hip/hip_runtime.h>
#include <hip/hip_bf16.h>

#define IN_F 8192
#define OUT_F 8192
#define SEQ 64
#define LORA_R 16

typedef __attribute__((ext_vector_type(4))) float f32x4;
typedef __attribute__((ext_vector_type(4))) int i32x4;
typedef __attribute__((ext_vector_type(8))) unsigned short u16x8;
typedef __attribute__((ext_vector_type(4))) unsigned short u16x4;
typedef _Float16 f16x2 __attribute__((ext_vector_type(2)));
typedef _Float16 f16x8 __attribute__((ext_vector_type(8)));

typedef __attribute__((address_space(3))) unsigned int lds_u32;
typedef const __attribute__((address_space(1))) unsigned int glb_u32;

__device__ __forceinline__ void gl_lds16(const void* g, void* l) {
    __builtin_amdgcn_global_load_lds((glb_u32*)g, (lds_u32*)l, 16, 0, 0);
}

// ---- prep: xb = fp16(x); t partials = x @ A^T (K split in 4). 256 blocks. ----
__global__ __launch_bounds__(256) void k_prep(
    const float* __restrict__ x, const float* __restrict__ A,
    unsigned short* __restrict__ xb, float* __restrict__ t) {
    __shared__ float part[64];
    const int s = blockIdx.x >> 2, p = blockIdx.x & 3;
    const int w = threadIdx.x >> 6, lane = threadIdx.x & 63;
    const int kbase = p * 2048 + w * 512;
    const float* xr = x + s * IN_F + kbase;

    f32x4 xv[2];
    #pragma unroll
    for (int j = 0; j < 2; ++j) {
        xv[j] = *(const f32x4*)(xr + j * 256 + lane * 4);
        u16x4 h;
        h[0] = __builtin_bit_cast(unsigned short, (_Float16)xv[j].x);
        h[1] = __builtin_bit_cast(unsigned short, (_Float16)xv[j].y);
        h[2] = __builtin_bit_cast(unsigned short, (_Float16)xv[j].z);
        h[3] = __builtin_bit_cast(unsigned short, (_Float16)xv[j].w);
        *(u16x4*)(xb + s * IN_F + kbase + j * 256 + lane * 4) = h;
    }

    float acc[LORA_R];
    #pragma unroll
    for (int r = 0; r < LORA_R; ++r) acc[r] = 0.f;
    #pragma unroll
    for (int r = 0; r < LORA_R; ++r) {
        const float* ar = A + r * IN_F + kbase;
        #pragma unroll
        for (int j = 0; j < 2; ++j) {
            f32x4 av = *(const f32x4*)(ar + j * 256 + lane * 4);
            acc[r] = fmaf(xv[j].x, av.x, acc[r]);
            acc[r] = fmaf(xv[j].y, av.y, acc[r]);
            acc[r] = fmaf(xv[j].z, av.z, acc[r]);
            acc[r] = fmaf(xv[j].w, av.w, acc[r]);
        }
    }
    #pragma unroll
    for (int r = 0; r < LORA_R; ++r) {
        float v = acc[r];
        #pragma unroll
        for (int off = 32; off; off >>= 1) v += __shfl_down(v, off, 64);
        if (lane == 0) part[w * 16 + r] = v;
    }
    __syncthreads();
    if (threadIdx.x < 16)
        t[s * 64 + p * 16 + threadIdx.x] = part[threadIdx.x] + part[16 + threadIdx.x] +
                                           part[32 + threadIdx.x] + part[48 + threadIdx.x];
}

// ---- main: 256 blocks (one 32-col n-tile each, FULL K), 512 thr = 8 waves ----
// Staging: global_load_lds w/ pre-XOR'd global src + swizzled LDS reads (rule #21).
// 3-deep pipeline over 4 LDS buffers, counted s_waitcnt vmcnt(6) (T4);
// tail peeled to vmcnt(3)/vmcnt(0).
// LDS (115200 B): xs 4x[64*128]f16 | wt 4x[32*64]int | scs [32*132]f32
// epilogue alias: accs [8][64*17] f32 over xs; t_red [64][16] f32 over scs.
__global__ __launch_bounds__(512, 2) void k_main(
    const int* __restrict__ packed, const float* __restrict__ scales,
    const unsigned short* __restrict__ xb, const float* __restrict__ t,
    const float* __restrict__ B, float* __restrict__ out) {
    __shared__ char lds[115200];
    _Float16* xs = (_Float16*)lds;            // 4 x 16384 B
    int* wt = (int*)(lds + 65536);            // 4 x 8192 B
    float* scs = (float*)(lds + 98304);       // 32*132*4 = 16896 B
    float* accs = (float*)lds;
    float* tred = scs;                        // epilogue alias, 4 KiB

    const int tid = threadIdx.x;
    const int n0 = blockIdx.x * 32;
    const int w = tid >> 6, lane = tid & 63;
    const int nh = w >> 2, wkk = w & 3;
    const int q = lane >> 4, c16 = lane & 15;

    // per-lane staging sources, 16B slot pre-XOR'd with (row&7)
    const int lrow = lane >> 4, lcol = lane & 15;
    const int xr0 = w * 8 + lrow, xr1 = xr0 + 4;
    const int wr  = w * 4 + lrow;
    const unsigned short* xg0 = xb + (size_t)xr0 * IN_F + ((lcol ^ (xr0 & 7)) << 3);
    const unsigned short* xg1 = xb + (size_t)xr1 * IN_F + ((lcol ^ (xr1 & 7)) << 3);
    const int* wgp = packed + (long)(n0 + wr) * (IN_F / 2) + ((lcol ^ (wr & 7)) << 2);

    // wave-uniform LDS dest bases (buffer 0)
    _Float16* xd0 = xs + w * 8 * 128;
    _Float16* xd1 = xd0 + 4 * 128;
    int* wd = wt + w * 256;

    // stage all 128 scales for this tile's 32 rows
    {
        int row = tid >> 4, g = tid & 15;
        const float* sp = scales + (n0 + row) * (IN_F / 64);
        *(f32x4*)(scs + row * 132 + g * 4)      = *(const f32x4*)(sp + g * 4);
        *(f32x4*)(scs + row * 132 + 64 + g * 4) = *(const f32x4*)(sp + 64 + g * 4);
    }

    f32x4 acc[4];
    #pragma unroll
    for (int mt = 0; mt < 4; ++mt) acc[mt] = (f32x4){0.f, 0.f, 0.f, 0.f};

    // loop-invariant swizzled read offsets
    const int pvo = (nh * 16 + c16) * 64 + ((wkk * 16 + q * 4) ^ ((c16 & 7) << 2));
    int afo[4];
    #pragma unroll
    for (int mt = 0; mt < 4; ++mt)
        afo[mt] = (mt * 16 + c16) * 128 + ((wkk * 32 + q * 8) ^ ((c16 & 7) << 3));
    const int sco = (nh * 16 + c16) * 132 + (wkk >> 1);

    // make scs visible before anyone reads it (LDS drain only — keep vm queue free)
    asm volatile("s_waitcnt lgkmcnt(0)" ::: "memory");
    __builtin_amdgcn_s_barrier();

    // prologue: stage chunks 0,1,2 -> buffers 0,1,2 (3-deep)
    #pragma unroll
    for (int c = 0; c < 3; ++c) {
        gl_lds16(xg0 + (size_t)c * 128, xd0 + c * 8192);
        gl_lds16(xg1 + (size_t)c * 128, xd1 + c * 8192);
        gl_lds16(wgp + c * 64,          wd  + c * 2048);
    }

    const f16x2 c1032 = {(_Float16)1032.0f, (_Float16)1032.0f};

    for (int kt = 0; kt < 64; ++kt) {
        // chunk kt resident (newer chunks may still fly); barrier; then issue kt+3
        if (kt < 62)       asm volatile("s_waitcnt vmcnt(6)" ::: "memory");
        else if (kt == 62) asm volatile("s_waitcnt vmcnt(3)" ::: "memory");
        else               asm volatile("s_waitcnt vmcnt(0)" ::: "memory");
        __builtin_amdgcn_s_barrier();
        __builtin_amdgcn_sched_barrier(0);
        const int cur = kt & 3;
        if (kt < 61) {
            const int nxt = (kt + 3) & 3;
            const size_t xoff = (size_t)(kt + 3) * 128;
            gl_lds16(xg0 + xoff, xd0 + nxt * 8192);
            gl_lds16(xg1 + xoff, xd1 + nxt * 8192);
            gl_lds16(wgp + (kt + 3) * 64, wd + nxt * 2048);
        }
        i32x4 pv = *(const i32x4*)(wt + cur * 2048 + pvo);
        float scf = scs[sco + kt * 2];
        _Float16 sch = (_Float16)scf;
        f16x2 sc2 = {sch, sch};
        f16x8 bf;
        #pragma unroll
        for (int m = 0; m < 4; ++m) {
            unsigned u = ((((unsigned)pv[m] << 12) | (unsigned)pv[m]) & 0x000F000Fu) | 0x64006400u;
            f16x2 h = __builtin_bit_cast(f16x2, u);
            h = (h - c1032) * sc2;          // exact (q-8)*scale
            bf[2 * m] = h.x;
            bf[2 * m + 1] = h.y;
        }
        const _Float16* xbase = xs + cur * 8192;
        #pragma unroll
        for (int mt = 0; mt < 4; ++mt) {
            f16x8 af = *(const f16x8*)(xbase + afo[mt]);
            acc[mt] = __builtin_amdgcn_mfma_f32_16x16x32_f16(af, bf, acc[mt], 0, 0, 0);
        }
    }
    __syncthreads();   // all waves done with xs/wt/scs before alias overwrite

    // epilogue: per-wave partials -> LDS (alias), t partial reduce -> LDS,
    // then reduce 4 k-waves + LoRA, direct store
    float* myacc = accs + w * (64 * 17);
    #pragma unroll
    for (int mt = 0; mt < 4; ++mt)
        #pragma unroll
        for (int r = 0; r < 4; ++r)
            myacc[(mt * 16 + q * 4 + r) * 17 + c16] = acc[mt][r];
    #pragma unroll
    for (int jj = 0; jj < 2; ++jj) {
        int p2 = tid + jj * 512;                  // 1024 = 64 s x 16 r
        const float* tp = t + (p2 >> 4) * 64 + (p2 & 15);
        tred[p2] = tp[0] + tp[16] + tp[32] + tp[48];
    }
    __syncthreads();

    #pragma unroll
    for (int j = 0; j < 4; ++j) {
        int p = tid + j * 512;                    // 2048 outputs: s in 0..63, c in 0..31
        int s = p >> 5, c = p & 31;
        const float* ab = accs + (c >> 4) * 4 * (64 * 17) + s * 17 + (c & 15);
        float v = ab[0] + ab[64 * 17] + ab[2 * 64 * 17] + ab[3 * 64 * 17];
        const float* trow = tred + s * 16;        // LDS-resident reduced t
        const float* bp = B + (n0 + c) * LORA_R;
        f32x4 t0 = *(const f32x4*)trow,        t1 = *(const f32x4*)(trow + 4);
        f32x4 t2 = *(const f32x4*)(trow + 8),  t3 = *(const f32x4*)(trow + 12);
        f32x4 b0 = *(const f32x4*)bp,       b1 = *(const f32x4*)(bp + 4);
        f32x4 b2 = *(const f32x4*)(bp + 8), b3 = *(const f32x4*)(bp + 12);
        float lr = t0.x * b0.x + t0.y * b0.y + t0.z * b0.z + t0.w * b0.w
                 + t1.x * b1.x + t1.y * b1.y + t1.z * b1.z + t1.w * b1.w
                 + t2.x * b2.x + t2.y * b2.y + t2.z * b2.z + t2.w * b2.w
                 + t3.x * b3.x + t3.y * b3.y + t3.z * b3.z + t3.w * b3.w;
        v += 2.0f * lr;
        out[s * OUT_F + n0 + c] = v;
    }
}

extern "C" void kernel_launch(void* const* d_in, const int* in_sizes, int n_in,
                              void* d_out, int out_size, void* d_ws, size_t ws_size,
                              hipStream_t stream) {
    const float* x      = (const float*)d_in[0];
    const int* packed   = (const int*)d_in[1];
    const float* scales = (const float*)d_in[2];
    const float* lora_A = (const float*)d_in[3];
    const float* lora_B = (const float*)d_in[4];
    float* out = (float*)d_out;

    unsigned short* xb = (unsigned short*)d_ws;                    // 1 MiB fp16 x
    float* t = (float*)((char*)d_ws + (size_t)SEQ * IN_F * 2);     // 16 KiB partials

    k_prep<<<256, 256, 0, stream>>>(x, lora_A, xb, t);
    k_main<<<256, 512, 0, stream>>>(packed, scales, xb, t, lora_B, out);
}